// Round 6
// baseline (112.906 us; speedup 1.0000x reference)
//
#include <hip/hip_runtime.h>
#include <math.h>

// Problem geometry
#define T_LEN   160000
#define NROW    128        // 64 rows of x then 64 rows of n
#define CH      32         // samples per chunk
#define NCH     5000       // CH*NCH == T_LEN
#define OWNS    79         // scan chunks per lane (64*79 = 5056 >= 5000)
#define O_CH    256        // emitted chunks per emit block
#define TILES   20         // ceil(5000/256)
#define NBLK    (NROW * TILES)   // 2560
#define SLOTS   258        // LDS chunks: c0-2 .. c0+255
#define XSF     (2 + SLOTS * CH) // 8258 floats = 33 KB -> 4 blocks/CU

// HP biquad: y = x - 2 x1 + x2 + 1.99599 y1 - 0.996 y2
#define C1_HP ( 1.99599)
#define C2_HP (-0.996)
#define C1F   ( 1.99599f)
#define C2F   (-0.996f)

__device__ __forceinline__ int swz(int i) { return i ^ ((i >> 5) & 31); }
__device__ __forceinline__ float clip1f(float v) { return fminf(fmaxf(v, -1.0f), 1.0f); }

// ---------------------------------------------------------------------------
// pass_a1: per (row, chunk) LOCAL stage-1 end state, f64 (zero y-init, true
// x-history from global). Writes e1[g] = (y[end-1], y[end-2])_local.
// ---------------------------------------------------------------------------
__global__ __launch_bounds__(256) void pass_a1(const float* __restrict__ x,
                                               const float* __restrict__ nn,
                                               double2* __restrict__ e1) {
  int g = blockIdx.x * blockDim.x + threadIdx.x;
  if (g >= NROW * NCH) return;
  int row = g / NCH, c = g % NCH;
  const float* src = (row < 64) ? (x + (size_t)row * T_LEN)
                                : (nn + (size_t)(row - 64) * T_LEN);
  const float* xp = src + c * CH;
  double x1 = 0.0, x2 = 0.0;
  if (c) { x1 = (double)xp[-1]; x2 = (double)xp[-2]; }
  double y1 = 0.0, y2 = 0.0;
#pragma unroll
  for (int j = 0; j < CH; j += 4) {
    float4 xv = *reinterpret_cast<const float4*>(xp + j);
#define A1STEP(XF) { double xt = (double)(XF); \
    double y = (xt - 2.0 * x1 + x2) + (C1_HP * y1 + C2_HP * y2); \
    x2 = x1; x1 = xt; y2 = y1; y1 = y; }
    A1STEP(xv.x) A1STEP(xv.y) A1STEP(xv.z) A1STEP(xv.w)
#undef A1STEP
  }
  e1[g] = make_double2(y1, y2);
}

// ---------------------------------------------------------------------------
// scan1: wave-parallel per-row combine, s_{c+1} = M s_c + e_c, M = A_hp^CH.
// f64 throughout; emits chunk-START states as float2 (quantization ~6e-8,
// amplified <=32 within a chunk -> ~2e-6).
// ---------------------------------------------------------------------------
__global__ __launch_bounds__(256) void scan1_kernel(const double2* __restrict__ e,
                                                    float2* __restrict__ s) {
  int tid = blockIdx.x * blockDim.x + threadIdx.x;
  int row = tid >> 6;
  int lane = tid & 63;
  if (row >= NROW) return;
  double pm2 = 0.0, pm1 = 0.0, p0 = 1.0;
#pragma unroll
  for (int k = 1; k <= CH; ++k) {
    double pn = C1_HP * p0 + C2_HP * pm1;
    pm2 = pm1; pm1 = p0; p0 = pn;
  }
  const double m00 = p0,  m01 = C2_HP * pm1;
  const double m10 = pm1, m11 = C2_HP * pm2;
  const double2* ep = e + (size_t)row * NCH;
  const int base = lane * OWNS;
  double f1 = 0.0, f2 = 0.0;
  for (int j = 0; j < OWNS; ++j) {
    int c = base + j;
    double2 ev = (c < NCH) ? ep[c] : make_double2(0.0, 0.0);
    double n1 = m00 * f1 + m01 * f2 + ev.x;
    double n2 = m10 * f1 + m11 * f2 + ev.y;
    f1 = n1; f2 = n2;
  }
  // B = M^OWNS by binary exponentiation
  double b00 = m00, b01 = m01, b10 = m10, b11 = m11;
  double r00 = 1.0, r01 = 0.0, r10 = 0.0, r11 = 1.0;
  int ee = OWNS;
  while (ee) {
    if (ee & 1) {
      double t00 = b00 * r00 + b01 * r10, t01 = b00 * r01 + b01 * r11;
      double t10 = b10 * r00 + b11 * r10, t11 = b10 * r01 + b11 * r11;
      r00 = t00; r01 = t01; r10 = t10; r11 = t11;
    }
    double q00 = b00 * b00 + b01 * b10, q01 = b00 * b01 + b01 * b11;
    double q10 = b10 * b00 + b11 * b10, q11 = b10 * b01 + b11 * b11;
    b00 = q00; b01 = q01; b10 = q10; b11 = q11;
    ee >>= 1;
  }
  b00 = r00; b01 = r01; b10 = r10; b11 = r11;
  double v1 = f1, v2 = f2;
#pragma unroll
  for (int off = 1; off < 64; off <<= 1) {
    double u1 = __shfl_up(v1, off);
    double u2 = __shfl_up(v2, off);
    if (lane >= off) {
      v1 += b00 * u1 + b01 * u2;
      v2 += b10 * u1 + b11 * u2;
    }
    double q00 = b00 * b00 + b01 * b10, q01 = b00 * b01 + b01 * b11;
    double q10 = b10 * b00 + b11 * b10, q11 = b10 * b01 + b11 * b11;
    b00 = q00; b01 = q01; b10 = q10; b11 = q11;
  }
  double g1 = __shfl_up(v1, 1);
  double g2 = __shfl_up(v2, 1);
  if (lane == 0) { g1 = 0.0; g2 = 0.0; }
  float2* sp = s + (size_t)row * NCH;
  double s1v = g1, s2v = g2;
  for (int j = 0; j < OWNS; ++j) {
    int c = base + j;
    if (c < NCH) {
      sp[c] = make_float2((float)s1v, (float)s2v);
      double2 ev = ep[c];
      double n1 = m00 * s1v + m01 * s2v + ev.x;
      double n2 = m10 * s1v + m11 * s2v + ev.y;
      s1v = n1; s2v = n2;
    }
  }
}

// ---------------------------------------------------------------------------
// emit: per block = (row, tile of 256 chunks). LDS holds 258 chunks of x.
// Phase A: each thread runs stage-1 (f32, EXACT seed from s1) over one chunk,
//   overwriting its LDS slots with clip(stage1).  (x-history read from global
//   to avoid in-place race on chunk-boundary samples.)
// Phase B1: stage-2 warm over the 2 predecessor chunks' clipped values
//   (zero z-init; pole^64 ~ 6e-6).  B2: stage-2 emit over own chunk, in place.
// Coalesced store of the 256 own chunks.
// ---------------------------------------------------------------------------
__global__ __launch_bounds__(256) void emit_kernel(const float* __restrict__ x,
                                                   const float* __restrict__ nn,
                                                   const float2* __restrict__ s1,
                                                   const float* __restrict__ cx,
                                                   const float* __restrict__ cn,
                                                   float* __restrict__ out) {
  __shared__ float xs[XSF];
  const int tid = threadIdx.x;
  const int b = blockIdx.x;
  const int row = b / TILES, tile = b % TILES;
  const int c0 = tile * O_CH;
  const long g0 = (long)(c0 - 2) * CH;        // global sample idx of LDS word 2
  const float* src = (row < 64) ? x + (size_t)row * T_LEN
                                : nn + (size_t)(row - 64) * T_LEN;
  const float2* srow = s1 + (size_t)row * NCH;

  // ---- load 258 chunks into swizzled LDS (coalesced float4) ----
  for (int k = tid; k < (SLOTS * CH) / 4; k += 256) {
    long gi = g0 + 4 * k;                     // multiple of 4; never straddles
    float4 v = make_float4(0.f, 0.f, 0.f, 0.f);
    if (gi >= 0 && gi < T_LEN) v = *reinterpret_cast<const float4*>(src + gi);
    int a = 2 + 4 * k;
    xs[swz(a)] = v.x; xs[swz(a + 1)] = v.y; xs[swz(a + 2)] = v.z; xs[swz(a + 3)] = v.w;
  }
  __syncthreads();

  // ---- phase A: stage-1 f32 per chunk, in place (x -> clip(stage1)) ----
  auto do_a = [&](int ca) {
    if (ca < 0 || ca >= NCH) return;
    float y1 = 0.f, y2 = 0.f;
    if (ca > 0) { float2 sv = srow[ca]; y1 = sv.x; y2 = sv.y; }
    long gb = (long)ca * CH;
    float x1 = (gb >= 1) ? src[gb - 1] : 0.f;
    float x2 = (gb >= 2) ? src[gb - 2] : 0.f;
    int a0 = 2 + CH * (ca - (c0 - 2));
#pragma unroll
    for (int j = 0; j < CH; ++j) {
      int aa = swz(a0 + j);
      float xt = xs[aa];
      float yy = (xt - 2.f * x1 + x2) + (C1F * y1 + C2F * y2);
      x2 = x1; x1 = xt; y2 = y1; y1 = yy;
      xs[aa] = clip1f(yy);
    }
  };
  do_a(c0 - 2 + tid);
  if (tid < 2) do_a(c0 + O_CH - 2 + tid);     // tail chunks c0+254, c0+255
  __syncthreads();

  // ---- phase B: stage-2 ----
  const float* cf = (row < 64) ? cx : cn;
  const float A1c = cf[0], A2c = cf[1], B1c = cf[2], B2c = cf[3];
  const int c = c0 + tid;
  const bool act = (c < NCH);
  float v1 = 0.f, v2 = 0.f, z1 = 0.f, z2 = 0.f;

  if (act && c >= 1) {                        // B1: warm over chunks cw..c-1
    int cw = (c >= 2) ? (c - 2) : 0;
    if (cw > 0) { float2 sv = srow[cw]; v1 = clip1f(sv.x); v2 = clip1f(sv.y); }
    int a0 = 2 + CH * (cw - (c0 - 2));
    int nwarm = (c - cw) * CH;                // 64 (or 32 for c==1)
    for (int j = 0; j < nwarm; ++j) {
      float vv = xs[swz(a0 + j)];
      float zz = vv + B1c * v1 + B2c * v2 - A1c * z1 - A2c * z2;
      v2 = v1; v1 = vv; z2 = z1; z1 = zz;
    }
  }
  __syncthreads();                            // B1 reads done before B2 writes
  if (act) {                                  // B2: emit own chunk, in place
    int a0 = 2 + CH * (tid + 2);
#pragma unroll
    for (int j = 0; j < CH; ++j) {
      int aa = swz(a0 + j);
      float vv = xs[aa];
      float zz = vv + B1c * v1 + B2c * v2 - A1c * z1 - A2c * z2;
      v2 = v1; v1 = vv; z2 = z1; z1 = zz;
      xs[aa] = clip1f(zz);
    }
  }
  __syncthreads();

  // ---- coalesced store of own 256 chunks ----
  float* orow = out + (size_t)row * T_LEN;
  const long tile_start = (long)c0 * CH;
  for (int k = tid; k < (O_CH * CH) / 4; k += 256) {
    long gi = tile_start + 4 * k;
    if (gi < T_LEN) {
      int a = 2 + 2 * CH + 4 * k;
      float4 v;
      v.x = xs[swz(a)]; v.y = xs[swz(a + 1)]; v.z = xs[swz(a + 2)]; v.w = xs[swz(a + 3)];
      *reinterpret_cast<float4*>(orow + gi) = v;
    }
  }
}

// ---------------------------------------------------------------------------
extern "C" void kernel_launch(void* const* d_in, const int* in_sizes, int n_in,
                              void* d_out, int out_size, void* d_ws, size_t ws_size,
                              hipStream_t stream) {
  const float* x  = (const float*)d_in[0];   // (64, 160000)
  const float* nn = (const float*)d_in[1];   // (64, 160000)
  const float* cx = (const float*)d_in[2];   // (4,) a1,a2,b1,b2
  const float* cn = (const float*)d_in[3];   // (4,)
  float* out = (float*)d_out;                // (128, 160000) flat

  // e1 (f64, 10.24 MB) aliases d_out: written by pass_a1, consumed by scan1,
  // then fully overwritten by emit. s1 (f32, 5.12 MB) in ws — read by emit
  // while out is being written.
  double2* e1 = (double2*)d_out;
  float2*  s1 = (float2*)d_ws;

  const int total = NROW * NCH;              // 640000
  const int blk = 256;
  const int nb = (total + blk - 1) / blk;    // 2500

  pass_a1<<<nb, blk, 0, stream>>>(x, nn, e1);
  scan1_kernel<<<(NROW * 64 + blk - 1) / blk, blk, 0, stream>>>(e1, s1);
  emit_kernel<<<NBLK, blk, 0, stream>>>(x, nn, s1, cx, cn, out);
}

// Round 7
// 81.187 us; speedup vs baseline: 1.3907x; 1.3907x over previous
//
#include <hip/hip_runtime.h>
#include <math.h>

// Problem geometry
#define T_LEN   160000
#define NROW    128        // 64 rows of x then 64 rows of n
#define CH      32         // samples per chunk
#define NCH     5000       // CH*NCH == T_LEN
#define OWNT    20         // chunks per thread in scan_row (256*20 = 5120 >= 5000)
#define O_CH    256        // emitted chunks per emit block
#define TILES   20         // ceil(5000/256)
#define NBLK    (NROW * TILES)   // 2560
#define SLOTS   258        // LDS chunks: c0-2 .. c0+255
#define NF4     (SLOTS * 8)      // 2064 float4 = 33 KB -> 4 blocks/CU

// HP biquad: y = x - 2 x1 + x2 + 1.99599 y1 - 0.996 y2
#define C1_HP ( 1.99599)
#define C2_HP (-0.996)
#define C1F   ( 1.99599f)
#define C2F   (-0.996f)

__device__ __forceinline__ int swz4(int F) { return F ^ ((F >> 3) & 7); }
__device__ __forceinline__ float clip1f(float v) { return fminf(fmaxf(v, -1.0f), 1.0f); }

// ---------------------------------------------------------------------------
// pass_a1: per (row, chunk) LOCAL stage-1 end state, f64 (zero y-init, true
// x-history from global). Writes e1[g] = (y[end-1], y[end-2])_local.
// ---------------------------------------------------------------------------
__global__ __launch_bounds__(256) void pass_a1(const float* __restrict__ x,
                                               const float* __restrict__ nn,
                                               double2* __restrict__ e1) {
  int g = blockIdx.x * blockDim.x + threadIdx.x;
  if (g >= NROW * NCH) return;
  int row = g / NCH, c = g % NCH;
  const float* src = (row < 64) ? (x + (size_t)row * T_LEN)
                                : (nn + (size_t)(row - 64) * T_LEN);
  const float* xp = src + c * CH;
  double x1 = 0.0, x2 = 0.0;
  if (c) { x1 = (double)xp[-1]; x2 = (double)xp[-2]; }
  double y1 = 0.0, y2 = 0.0;
#pragma unroll
  for (int j = 0; j < CH; j += 4) {
    float4 xv = *reinterpret_cast<const float4*>(xp + j);
#define A1STEP(XF) { double xt = (double)(XF); \
    double y = (xt - 2.0 * x1 + x2) + (C1_HP * y1 + C2_HP * y2); \
    x2 = x1; x1 = xt; y2 = y1; y1 = y; }
    A1STEP(xv.x) A1STEP(xv.y) A1STEP(xv.z) A1STEP(xv.w)
#undef A1STEP
  }
  e1[g] = make_double2(y1, y2);
}

// ---------------------------------------------------------------------------
// scan_row: one block (4 waves) per row. Thread owns OWNT=20 chunks:
// local affine compose, wave-level affine Kogge-Stone (matrix+vector pairs),
// cross-wave combine via LDS, then re-walk emitting chunk-start states (f32).
// ---------------------------------------------------------------------------
__global__ __launch_bounds__(256) void scan_row(const double2* __restrict__ e,
                                                float2* __restrict__ s) {
  __shared__ double wm[4][6];      // per-wave map: P00,P01,P10,P11,V1,V2
  const int t = threadIdx.x, row = blockIdx.x;
  const int lane = t & 63, wv = t >> 6;
  // M = A_hp^CH via p-recurrence
  double pm2 = 0.0, pm1 = 0.0, p0 = 1.0;
#pragma unroll
  for (int k = 1; k <= CH; ++k) {
    double pn = C1_HP * p0 + C2_HP * pm1;
    pm2 = pm1; pm1 = p0; p0 = pn;
  }
  const double m00 = p0,  m01 = C2_HP * pm1;
  const double m10 = pm1, m11 = C2_HP * pm2;
  const double2* ep = e + (size_t)row * NCH;
  const int base = t * OWNT;
  // local compose f = sum_j M^{OWNT-1-j} e_{base+j}
  double f1 = 0.0, f2 = 0.0;
  for (int j = 0; j < OWNT; ++j) {
    int c = base + j;
    double2 ev = (c < NCH) ? ep[c] : make_double2(0.0, 0.0);
    double n1 = m00 * f1 + m01 * f2 + ev.x;
    double n2 = m10 * f1 + m11 * f2 + ev.y;
    f1 = n1; f2 = n2;
  }
  // B = M^OWNT by binary exponentiation
  double b00 = m00, b01 = m01, b10 = m10, b11 = m11;
  double r00 = 1.0, r01 = 0.0, r10 = 0.0, r11 = 1.0;
  int ee = OWNT;
  while (ee) {
    if (ee & 1) {
      double t00 = b00 * r00 + b01 * r10, t01 = b00 * r01 + b01 * r11;
      double t10 = b10 * r00 + b11 * r10, t11 = b10 * r01 + b11 * r11;
      r00 = t00; r01 = t01; r10 = t10; r11 = t11;
    }
    double q00 = b00 * b00 + b01 * b10, q01 = b00 * b01 + b01 * b11;
    double q10 = b10 * b00 + b11 * b10, q11 = b10 * b01 + b11 * b11;
    b00 = q00; b01 = q01; b10 = q10; b11 = q11;
    ee >>= 1;
  }
  // affine KS over the wave: lane map (P,V), H_l = G_l ∘ ... ∘ G_0
  double P00 = r00, P01 = r01, P10 = r10, P11 = r11, V1 = f1, V2 = f2;
#pragma unroll
  for (int off = 1; off < 64; off <<= 1) {
    double u00 = __shfl_up(P00, off), u01 = __shfl_up(P01, off);
    double u10 = __shfl_up(P10, off), u11 = __shfl_up(P11, off);
    double uv1 = __shfl_up(V1, off),  uv2 = __shfl_up(V2, off);
    if (lane >= off) {
      double nv1 = P00 * uv1 + P01 * uv2 + V1;
      double nv2 = P10 * uv1 + P11 * uv2 + V2;
      double n00 = P00 * u00 + P01 * u10, n01 = P00 * u01 + P01 * u11;
      double n10 = P10 * u00 + P11 * u10, n11 = P10 * u01 + P11 * u11;
      P00 = n00; P01 = n01; P10 = n10; P11 = n11; V1 = nv1; V2 = nv2;
    }
  }
  if (lane == 63) {
    wm[wv][0] = P00; wm[wv][1] = P01; wm[wv][2] = P10; wm[wv][3] = P11;
    wm[wv][4] = V1;  wm[wv][5] = V2;
  }
  __syncthreads();
  // wave-start state S_w = composition of prior wave maps applied to 0
  double S1 = 0.0, S2 = 0.0;
  for (int w = 0; w < wv; ++w) {
    double n1 = wm[w][0] * S1 + wm[w][1] * S2 + wm[w][4];
    double n2 = wm[w][2] * S1 + wm[w][3] * S2 + wm[w][5];
    S1 = n1; S2 = n2;
  }
  // exclusive lane map -> thread-start state
  double q00 = __shfl_up(P00, 1), q01 = __shfl_up(P01, 1);
  double q10 = __shfl_up(P10, 1), q11 = __shfl_up(P11, 1);
  double qv1 = __shfl_up(V1, 1),  qv2 = __shfl_up(V2, 1);
  double st1, st2;
  if (lane == 0) { st1 = S1; st2 = S2; }
  else { st1 = q00 * S1 + q01 * S2 + qv1; st2 = q10 * S1 + q11 * S2 + qv2; }
  // re-walk: emit chunk-start states
  float2* sp = s + (size_t)row * NCH;
  double s1v = st1, s2v = st2;
  for (int j = 0; j < OWNT; ++j) {
    int c = base + j;
    if (c < NCH) {
      sp[c] = make_float2((float)s1v, (float)s2v);
      double2 ev = ep[c];
      double n1 = m00 * s1v + m01 * s2v + ev.x;
      double n2 = m10 * s1v + m11 * s2v + ev.y;
      s1v = n1; s2v = n2;
    }
  }
}

// ---------------------------------------------------------------------------
// emit: per block = (row, tile of 256 chunks). float4 LDS, quad-XOR swizzle.
// Phase A: slot transform x -> clip(stage1), f32, exact seed, all in regs.
// Phase B1: stage-2 warm over 2 predecessor chunks (reads LDS in batches).
// Phase B2: stage-2 emit over own chunk (batch read/modify/write own slot).
// Coalesced float4 load/store of the tile.
// ---------------------------------------------------------------------------
__global__ __launch_bounds__(256) void emit_kernel(const float* __restrict__ x,
                                                   const float* __restrict__ nn,
                                                   const float2* __restrict__ s1,
                                                   const float* __restrict__ cx,
                                                   const float* __restrict__ cn,
                                                   float* __restrict__ out) {
  __shared__ float4 xs4[NF4];
  const int tid = threadIdx.x;
  const int b = blockIdx.x;
  const int row = b / TILES, tile = b % TILES;
  const int c0 = tile * O_CH;
  const long g0 = (long)(c0 - 2) * CH;        // sample index of slot 0, word 0
  const float* src = (row < 64) ? x + (size_t)row * T_LEN
                                : nn + (size_t)(row - 64) * T_LEN;
  const float2* srow = s1 + (size_t)row * NCH;

  // ---- coalesced load of 258 chunks ----
  for (int k = tid; k < NF4; k += 256) {
    long gi = g0 + 4L * k;
    float4 v = make_float4(0.f, 0.f, 0.f, 0.f);
    if (gi >= 0 && gi < T_LEN) v = *reinterpret_cast<const float4*>(src + gi);
    xs4[swz4(k)] = v;
  }
  __syncthreads();

  const float* cf = (row < 64) ? cx : cn;
  const float A1c = cf[0], A2c = cf[1], B1c = cf[2], B2c = cf[3];
  const int c = c0 + tid;
  const bool act = (c < NCH);

#define S1STEP(XT, OT) { float xt_ = (XT); \
    float yy = (xt_ - 2.f * x1 + x2) + (C1F * y1 + C2F * y2); \
    x2 = x1; x1 = xt_; y2 = y1; y1 = yy; OT = clip1f(yy); }
#define S2W(VV) { float vv_ = (VV); \
    float zz = vv_ + B1c * v1 + B2c * v2 - A1c * z1 - A2c * z2; \
    v2 = v1; v1 = vv_; z2 = z1; z1 = zz; }
#define S2E(VV, OT) { float vv_ = (VV); \
    float zz = vv_ + B1c * v1 + B2c * v2 - A1c * z1 - A2c * z2; \
    v2 = v1; v1 = vv_; z2 = z1; z1 = zz; OT = clip1f(zz); }

  // ---- phase A: stage-1 slot transform (x -> clip(stage1)), registers ----
  const int npass = (tid < 2) ? 2 : 1;
  for (int p = 0; p < npass; ++p) {
    const int slot = (p == 0) ? tid : (256 + tid);
    const int ca = c0 - 2 + slot;
    if (ca < 0 || ca >= NCH) continue;
    float4 a[8];
#pragma unroll
    for (int q = 0; q < 8; ++q) a[q] = xs4[swz4(slot * 8 + q)];
    float y1 = 0.f, y2 = 0.f;
    if (ca > 0) { float2 sv = srow[ca]; y1 = sv.x; y2 = sv.y; }
    const long gb = (long)ca * CH;
    float x1 = (ca > 0) ? src[gb - 1] : 0.f;
    float x2 = (ca > 0) ? src[gb - 2] : 0.f;
    float4 o[8];
#pragma unroll
    for (int q = 0; q < 8; ++q) {
      S1STEP(a[q].x, o[q].x) S1STEP(a[q].y, o[q].y)
      S1STEP(a[q].z, o[q].z) S1STEP(a[q].w, o[q].w)
    }
#pragma unroll
    for (int q = 0; q < 8; ++q) xs4[swz4(slot * 8 + q)] = o[q];
  }
  __syncthreads();

  // ---- phase B1: stage-2 warm over chunks c-2, c-1 (slots tid, tid+1) ----
  float v1 = 0.f, v2 = 0.f, z1 = 0.f, z2 = 0.f;
  if (act) {
    if (c >= 3) { float2 sv = srow[c - 2]; v1 = clip1f(sv.x); v2 = clip1f(sv.y); }
#pragma unroll
    for (int si = 0; si < 2; ++si) {
      const int slot = tid + si;
      float4 w[8];
#pragma unroll
      for (int q = 0; q < 8; ++q) w[q] = xs4[swz4(slot * 8 + q)];
#pragma unroll
      for (int q = 0; q < 8; ++q) {
        S2W(w[q].x) S2W(w[q].y) S2W(w[q].z) S2W(w[q].w)
      }
    }
  }
  __syncthreads();

  // ---- phase B2: stage-2 emit over own chunk (slot tid+2), in place ----
  if (act) {
    const int slot = tid + 2;
    float4 w[8];
#pragma unroll
    for (int q = 0; q < 8; ++q) w[q] = xs4[swz4(slot * 8 + q)];
#pragma unroll
    for (int q = 0; q < 8; ++q) {
      S2E(w[q].x, w[q].x) S2E(w[q].y, w[q].y)
      S2E(w[q].z, w[q].z) S2E(w[q].w, w[q].w)
    }
#pragma unroll
    for (int q = 0; q < 8; ++q) xs4[swz4(slot * 8 + q)] = w[q];
  }
  __syncthreads();

#undef S1STEP
#undef S2W
#undef S2E

  // ---- coalesced store of own 256 chunks (slots 2..257) ----
  float* orow = out + (size_t)row * T_LEN;
  const long tile_start = (long)c0 * CH;
  for (int k = tid; k < O_CH * 8; k += 256) {
    long gi = tile_start + 4L * k;
    if (gi < T_LEN)
      *reinterpret_cast<float4*>(orow + gi) = xs4[swz4(16 + k)];
  }
}

// ---------------------------------------------------------------------------
extern "C" void kernel_launch(void* const* d_in, const int* in_sizes, int n_in,
                              void* d_out, int out_size, void* d_ws, size_t ws_size,
                              hipStream_t stream) {
  const float* x  = (const float*)d_in[0];   // (64, 160000)
  const float* nn = (const float*)d_in[1];   // (64, 160000)
  const float* cx = (const float*)d_in[2];   // (4,) a1,a2,b1,b2
  const float* cn = (const float*)d_in[3];   // (4,)
  float* out = (float*)d_out;                // (128, 160000) flat

  // e1 (f64, 10.24 MB) aliases d_out: written by pass_a1, consumed by
  // scan_row, then fully overwritten by emit. s1 (f32, 5.12 MB) in ws.
  double2* e1 = (double2*)d_out;
  float2*  s1 = (float2*)d_ws;

  const int total = NROW * NCH;              // 640000
  const int blk = 256;
  const int nb = (total + blk - 1) / blk;    // 2500

  pass_a1<<<nb, blk, 0, stream>>>(x, nn, e1);
  scan_row<<<NROW, blk, 0, stream>>>(e1, s1);
  emit_kernel<<<NBLK, blk, 0, stream>>>(x, nn, s1, cx, cn, out);
}

// Round 8
// 74.503 us; speedup vs baseline: 1.5154x; 1.0897x over previous
//
#include <hip/hip_runtime.h>
#include <math.h>

// Problem geometry
#define T_LEN   160000
#define NROW    128        // 64 rows of x then 64 rows of n
#define CH      32         // samples per chunk
#define NCH     5000       // CH*NCH == T_LEN
#define OWNT    20         // chunks per thread in scan_row (256*20 = 5120 >= 5000)
#define O_CH    256        // emitted chunks per emit block
#define TILES   20         // ceil(5000/256)
#define NBLK    (NROW * TILES)   // 2560
#define SLOTS   258        // LDS chunks: c0-2 .. c0+255
#define NF4     (SLOTS * 8)      // 2064 float4 = 33 KB -> 4 blocks/CU

// HP biquad: y = x - 2 x1 + x2 + 1.99599 y1 - 0.996 y2
#define C1_HP ( 1.99599)
#define C2_HP (-0.996)
#define C1F   ( 1.99599f)
#define C2F   (-0.996f)

__device__ __forceinline__ int swz4(int F) { return F ^ ((F >> 3) & 7); }
__device__ __forceinline__ float clip1f(float v) { return fminf(fmaxf(v, -1.0f), 1.0f); }

// ---------------------------------------------------------------------------
// pass_a1: per (row, chunk) LOCAL stage-1 end state (zero y-init, true
// x-history). FIR part f32 (inputs exact), y-recurrence f64.
// ---------------------------------------------------------------------------
__global__ __launch_bounds__(256) void pass_a1(const float* __restrict__ x,
                                               const float* __restrict__ nn,
                                               double2* __restrict__ e1) {
  int g = blockIdx.x * blockDim.x + threadIdx.x;
  if (g >= NROW * NCH) return;
  int row = g / NCH, c = g % NCH;
  const float* src = (row < 64) ? (x + (size_t)row * T_LEN)
                                : (nn + (size_t)(row - 64) * T_LEN);
  const float* xp = src + c * CH;
  float x1 = 0.f, x2 = 0.f;
  if (c) { x1 = xp[-1]; x2 = xp[-2]; }
  double y1 = 0.0, y2 = 0.0;
#pragma unroll
  for (int j = 0; j < CH; j += 4) {
    float4 xv = *reinterpret_cast<const float4*>(xp + j);
#define A1STEP(XF) { float xt = (XF); \
    float fir = (xt - 2.f * x1 + x2); \
    double y = (double)fir + (C1_HP * y1 + C2_HP * y2); \
    x2 = x1; x1 = xt; y2 = y1; y1 = y; }
    A1STEP(xv.x) A1STEP(xv.y) A1STEP(xv.z) A1STEP(xv.w)
#undef A1STEP
  }
  e1[g] = make_double2(y1, y2);
}

// ---------------------------------------------------------------------------
// scan_row: one block (4 waves) per row. Thread owns OWNT=20 chunks:
// local affine compose, wave-level affine Kogge-Stone (matrix+vector),
// cross-wave combine via LDS, then re-walk emitting chunk-start states (f32).
// ---------------------------------------------------------------------------
__global__ __launch_bounds__(256) void scan_row(const double2* __restrict__ e,
                                                float2* __restrict__ s) {
  __shared__ double wm[4][6];      // per-wave map: P00,P01,P10,P11,V1,V2
  const int t = threadIdx.x, row = blockIdx.x;
  const int lane = t & 63, wv = t >> 6;
  // M = A_hp^CH via p-recurrence
  double pm2 = 0.0, pm1 = 0.0, p0 = 1.0;
#pragma unroll
  for (int k = 1; k <= CH; ++k) {
    double pn = C1_HP * p0 + C2_HP * pm1;
    pm2 = pm1; pm1 = p0; p0 = pn;
  }
  const double m00 = p0,  m01 = C2_HP * pm1;
  const double m10 = pm1, m11 = C2_HP * pm2;
  const double2* ep = e + (size_t)row * NCH;
  const int base = t * OWNT;
  double f1 = 0.0, f2 = 0.0;
  for (int j = 0; j < OWNT; ++j) {
    int c = base + j;
    double2 ev = (c < NCH) ? ep[c] : make_double2(0.0, 0.0);
    double n1 = m00 * f1 + m01 * f2 + ev.x;
    double n2 = m10 * f1 + m11 * f2 + ev.y;
    f1 = n1; f2 = n2;
  }
  // B = M^OWNT by binary exponentiation
  double b00 = m00, b01 = m01, b10 = m10, b11 = m11;
  double r00 = 1.0, r01 = 0.0, r10 = 0.0, r11 = 1.0;
  int ee = OWNT;
  while (ee) {
    if (ee & 1) {
      double t00 = b00 * r00 + b01 * r10, t01 = b00 * r01 + b01 * r11;
      double t10 = b10 * r00 + b11 * r10, t11 = b10 * r01 + b11 * r11;
      r00 = t00; r01 = t01; r10 = t10; r11 = t11;
    }
    double q00 = b00 * b00 + b01 * b10, q01 = b00 * b01 + b01 * b11;
    double q10 = b10 * b00 + b11 * b10, q11 = b10 * b01 + b11 * b11;
    b00 = q00; b01 = q01; b10 = q10; b11 = q11;
    ee >>= 1;
  }
  // affine KS over the wave
  double P00 = r00, P01 = r01, P10 = r10, P11 = r11, V1 = f1, V2 = f2;
#pragma unroll
  for (int off = 1; off < 64; off <<= 1) {
    double u00 = __shfl_up(P00, off), u01 = __shfl_up(P01, off);
    double u10 = __shfl_up(P10, off), u11 = __shfl_up(P11, off);
    double uv1 = __shfl_up(V1, off),  uv2 = __shfl_up(V2, off);
    if (lane >= off) {
      double nv1 = P00 * uv1 + P01 * uv2 + V1;
      double nv2 = P10 * uv1 + P11 * uv2 + V2;
      double n00 = P00 * u00 + P01 * u10, n01 = P00 * u01 + P01 * u11;
      double n10 = P10 * u00 + P11 * u10, n11 = P10 * u01 + P11 * u11;
      P00 = n00; P01 = n01; P10 = n10; P11 = n11; V1 = nv1; V2 = nv2;
    }
  }
  if (lane == 63) {
    wm[wv][0] = P00; wm[wv][1] = P01; wm[wv][2] = P10; wm[wv][3] = P11;
    wm[wv][4] = V1;  wm[wv][5] = V2;
  }
  __syncthreads();
  double S1 = 0.0, S2 = 0.0;
  for (int w = 0; w < wv; ++w) {
    double n1 = wm[w][0] * S1 + wm[w][1] * S2 + wm[w][4];
    double n2 = wm[w][2] * S1 + wm[w][3] * S2 + wm[w][5];
    S1 = n1; S2 = n2;
  }
  double q00 = __shfl_up(P00, 1), q01 = __shfl_up(P01, 1);
  double q10 = __shfl_up(P10, 1), q11 = __shfl_up(P11, 1);
  double qv1 = __shfl_up(V1, 1),  qv2 = __shfl_up(V2, 1);
  double st1, st2;
  if (lane == 0) { st1 = S1; st2 = S2; }
  else { st1 = q00 * S1 + q01 * S2 + qv1; st2 = q10 * S1 + q11 * S2 + qv2; }
  float2* sp = s + (size_t)row * NCH;
  double s1v = st1, s2v = st2;
  for (int j = 0; j < OWNT; ++j) {
    int c = base + j;
    if (c < NCH) {
      sp[c] = make_float2((float)s1v, (float)s2v);
      double2 ev = ep[c];
      double n1 = m00 * s1v + m01 * s2v + ev.x;
      double n2 = m10 * s1v + m11 * s2v + ev.y;
      s1v = n1; s2v = n2;
    }
  }
}

// ---------------------------------------------------------------------------
// emit: per block = (row, tile of 256 chunks). x tile in swizzled float4 LDS.
// SINGLE fused compute phase: each thread runs stage1+stage2 over its 2 warm
// chunks + own chunk (96 steps, registers only; stage-1 seeded exactly from
// s1[c-2], stage-2 warm from zero (pole^64 ~ 6e-6)). Own-chunk results kept
// in registers across a barrier, then written back & stored coalesced.
// ---------------------------------------------------------------------------
__global__ __launch_bounds__(256) void emit_kernel(const float* __restrict__ x,
                                                   const float* __restrict__ nn,
                                                   const float2* __restrict__ s1,
                                                   const float* __restrict__ cx,
                                                   const float* __restrict__ cn,
                                                   float* __restrict__ out) {
  __shared__ float4 xs4[NF4];
  const int tid = threadIdx.x;
  const int b = blockIdx.x;
  const int row = b / TILES, tile = b % TILES;
  const int c0 = tile * O_CH;
  const long g0 = (long)(c0 - 2) * CH;        // sample index of slot 0, word 0
  const float* src = (row < 64) ? x + (size_t)row * T_LEN
                                : nn + (size_t)(row - 64) * T_LEN;
  const float2* srow = s1 + (size_t)row * NCH;

  // ---- coalesced load of 258 chunks into swizzled LDS ----
  for (int k = tid; k < NF4; k += 256) {
    long gi = g0 + 4L * k;
    float4 v = make_float4(0.f, 0.f, 0.f, 0.f);
    if (gi >= 0 && gi < T_LEN) v = *reinterpret_cast<const float4*>(src + gi);
    xs4[swz4(k)] = v;
  }
  __syncthreads();

  const float* cf = (row < 64) ? cx : cn;
  const float A1c = cf[0], A2c = cf[1], B1c = cf[2], B2c = cf[3];
  const int c = c0 + tid;
  const bool act = (c < NCH);

  float4 o[8];                                // own-chunk results (live across barrier)

#define WSTEP(XT) { float xt_ = (XT); \
    float fir = (xt_ - 2.f * x1 + x2) + (C1F * y1 + C2F * y2); \
    x2 = x1; x1 = xt_; y2 = y1; y1 = fir; \
    float vv = clip1f(fir); \
    float zz = vv + B1c * v1 + B2c * v2 - A1c * z1 - A2c * z2; \
    v2 = v1; v1 = vv; z2 = z1; z1 = zz; }
#define ESTEP(XT, OT) { float xt_ = (XT); \
    float fir = (xt_ - 2.f * x1 + x2) + (C1F * y1 + C2F * y2); \
    x2 = x1; x1 = xt_; y2 = y1; y1 = fir; \
    float vv = clip1f(fir); \
    float zz = vv + B1c * v1 + B2c * v2 - A1c * z1 - A2c * z2; \
    v2 = v1; v1 = vv; z2 = z1; z1 = zz; OT = clip1f(zz); }

  if (act) {
    float y1 = 0.f, y2 = 0.f, x1 = 0.f, x2 = 0.f;   // stage-1 state
    float v1 = 0.f, v2 = 0.f, z1 = 0.f, z2 = 0.f;   // stage-2 state
    const int cw = (c >= 2) ? (c - 2) : 0;
    if (cw > 0) {
      float2 sv = srow[cw];
      y1 = sv.x; y2 = sv.y;
      v1 = clip1f(sv.x); v2 = clip1f(sv.y);
      const long gb = (long)cw * CH;
      x1 = src[gb - 1]; x2 = src[gb - 2];
    }
    // warm chunks c-2, c-1 (skip negatives; tile 0 only)
#pragma unroll
    for (int si = 0; si < 2; ++si) {
      const int cc = c - 2 + si;
      if (cc >= 0) {
        const int slot = tid + si;
        float4 a[8];
#pragma unroll
        for (int q = 0; q < 8; ++q) a[q] = xs4[swz4(slot * 8 + q)];
#pragma unroll
        for (int q = 0; q < 8; ++q) {
          WSTEP(a[q].x) WSTEP(a[q].y) WSTEP(a[q].z) WSTEP(a[q].w)
        }
      }
    }
    // own chunk c (slot tid+2): results into registers o[8]
    {
      const int slot = tid + 2;
#pragma unroll
      for (int q = 0; q < 8; ++q) o[q] = xs4[swz4(slot * 8 + q)];
#pragma unroll
      for (int q = 0; q < 8; ++q) {
        ESTEP(o[q].x, o[q].x) ESTEP(o[q].y, o[q].y)
        ESTEP(o[q].z, o[q].z) ESTEP(o[q].w, o[q].w)
      }
    }
  }
#undef WSTEP
#undef ESTEP
  __syncthreads();                            // all warm reads done
  if (act) {
    const int slot = tid + 2;
#pragma unroll
    for (int q = 0; q < 8; ++q) xs4[swz4(slot * 8 + q)] = o[q];
  }
  __syncthreads();

  // ---- coalesced store of own 256 chunks (slots 2..257) ----
  float* orow = out + (size_t)row * T_LEN;
  const long tile_start = (long)c0 * CH;
  for (int k = tid; k < O_CH * 8; k += 256) {
    long gi = tile_start + 4L * k;
    if (gi < T_LEN)
      *reinterpret_cast<float4*>(orow + gi) = xs4[swz4(16 + k)];
  }
}

// ---------------------------------------------------------------------------
extern "C" void kernel_launch(void* const* d_in, const int* in_sizes, int n_in,
                              void* d_out, int out_size, void* d_ws, size_t ws_size,
                              hipStream_t stream) {
  const float* x  = (const float*)d_in[0];   // (64, 160000)
  const float* nn = (const float*)d_in[1];   // (64, 160000)
  const float* cx = (const float*)d_in[2];   // (4,) a1,a2,b1,b2
  const float* cn = (const float*)d_in[3];   // (4,)
  float* out = (float*)d_out;                // (128, 160000) flat

  // e1 (f64, 10.24 MB) aliases d_out: written by pass_a1, consumed by
  // scan_row, then fully overwritten by emit. s1 (f32, 5.12 MB) in ws.
  double2* e1 = (double2*)d_out;
  float2*  s1 = (float2*)d_ws;

  const int total = NROW * NCH;              // 640000
  const int blk = 256;
  const int nb = (total + blk - 1) / blk;    // 2500

  pass_a1<<<nb, blk, 0, stream>>>(x, nn, e1);
  scan_row<<<NROW, blk, 0, stream>>>(e1, s1);
  emit_kernel<<<NBLK, blk, 0, stream>>>(x, nn, s1, cx, cn, out);
}

// Round 9
// 65.929 us; speedup vs baseline: 1.7125x; 1.1300x over previous
//
#include <hip/hip_runtime.h>
#include <math.h>

// Problem geometry
#define T_LEN   160000
#define NROW    128        // 64 rows of x then 64 rows of n
#define CH      32         // samples per chunk
#define NCH     5000       // CH*NCH == T_LEN
#define OWNT    20         // chunks per thread in scan_row (256*20 >= 5000)
#define O_CH    252        // emitted chunks per emit block
#define SLOTS   254        // LDS chunks: c0-2 .. c0+251
#define NF4     (SLOTS * 8)      // 2032 float4 = 32512 B -> 5 blocks/CU
#define TILES   20               // ceil(5000/252)
#define NBLK    (NROW * TILES)   // 2560

// HP biquad: y = x - 2 x1 + x2 + 1.99599 y1 - 0.996 y2
#define C1_HP ( 1.99599)
#define C2_HP (-0.996)
#define C1F   ( 1.99599f)
#define C2F   (-0.996f)

__device__ __forceinline__ int swz4(int F) { return F ^ ((F >> 3) & 7); }
__device__ __forceinline__ float clip1f(float v) { return fminf(fmaxf(v, -1.0f), 1.0f); }

// ---------------------------------------------------------------------------
// pass_a1: per (row, chunk) LOCAL stage-1 end state (zero y-init, true
// x-history). FIR part f32 (inputs exact), y-recurrence f64.
// ---------------------------------------------------------------------------
__global__ __launch_bounds__(256) void pass_a1(const float* __restrict__ x,
                                               const float* __restrict__ nn,
                                               double2* __restrict__ e1) {
  int g = blockIdx.x * blockDim.x + threadIdx.x;
  if (g >= NROW * NCH) return;
  int row = g / NCH, c = g % NCH;
  const float* src = (row < 64) ? (x + (size_t)row * T_LEN)
                                : (nn + (size_t)(row - 64) * T_LEN);
  const float* xp = src + c * CH;
  float x1 = 0.f, x2 = 0.f;
  if (c) { x1 = xp[-1]; x2 = xp[-2]; }
  double y1 = 0.0, y2 = 0.0;
#pragma unroll
  for (int j = 0; j < CH; j += 4) {
    float4 xv = *reinterpret_cast<const float4*>(xp + j);
#define A1STEP(XF) { float xt = (XF); \
    float fir = (xt - 2.f * x1 + x2); \
    double y = (double)fir + (C1_HP * y1 + C2_HP * y2); \
    x2 = x1; x1 = xt; y2 = y1; y1 = y; }
    A1STEP(xv.x) A1STEP(xv.y) A1STEP(xv.z) A1STEP(xv.w)
#undef A1STEP
  }
  e1[g] = make_double2(y1, y2);
}

// ---------------------------------------------------------------------------
// scan_row: one block (4 waves) per row; affine Kogge-Stone over chunk maps;
// emits exact chunk-start states (f32).
// ---------------------------------------------------------------------------
__global__ __launch_bounds__(256) void scan_row(const double2* __restrict__ e,
                                                float2* __restrict__ s) {
  __shared__ double wm[4][6];
  const int t = threadIdx.x, row = blockIdx.x;
  const int lane = t & 63, wv = t >> 6;
  double pm2 = 0.0, pm1 = 0.0, p0 = 1.0;
#pragma unroll
  for (int k = 1; k <= CH; ++k) {
    double pn = C1_HP * p0 + C2_HP * pm1;
    pm2 = pm1; pm1 = p0; p0 = pn;
  }
  const double m00 = p0,  m01 = C2_HP * pm1;
  const double m10 = pm1, m11 = C2_HP * pm2;
  const double2* ep = e + (size_t)row * NCH;
  const int base = t * OWNT;
  double f1 = 0.0, f2 = 0.0;
  for (int j = 0; j < OWNT; ++j) {
    int c = base + j;
    double2 ev = (c < NCH) ? ep[c] : make_double2(0.0, 0.0);
    double n1 = m00 * f1 + m01 * f2 + ev.x;
    double n2 = m10 * f1 + m11 * f2 + ev.y;
    f1 = n1; f2 = n2;
  }
  double b00 = m00, b01 = m01, b10 = m10, b11 = m11;
  double r00 = 1.0, r01 = 0.0, r10 = 0.0, r11 = 1.0;
  int ee = OWNT;
  while (ee) {
    if (ee & 1) {
      double t00 = b00 * r00 + b01 * r10, t01 = b00 * r01 + b01 * r11;
      double t10 = b10 * r00 + b11 * r10, t11 = b10 * r01 + b11 * r11;
      r00 = t00; r01 = t01; r10 = t10; r11 = t11;
    }
    double q00 = b00 * b00 + b01 * b10, q01 = b00 * b01 + b01 * b11;
    double q10 = b10 * b00 + b11 * b10, q11 = b10 * b01 + b11 * b11;
    b00 = q00; b01 = q01; b10 = q10; b11 = q11;
    ee >>= 1;
  }
  double P00 = r00, P01 = r01, P10 = r10, P11 = r11, V1 = f1, V2 = f2;
#pragma unroll
  for (int off = 1; off < 64; off <<= 1) {
    double u00 = __shfl_up(P00, off), u01 = __shfl_up(P01, off);
    double u10 = __shfl_up(P10, off), u11 = __shfl_up(P11, off);
    double uv1 = __shfl_up(V1, off),  uv2 = __shfl_up(V2, off);
    if (lane >= off) {
      double nv1 = P00 * uv1 + P01 * uv2 + V1;
      double nv2 = P10 * uv1 + P11 * uv2 + V2;
      double n00 = P00 * u00 + P01 * u10, n01 = P00 * u01 + P01 * u11;
      double n10 = P10 * u00 + P11 * u10, n11 = P10 * u01 + P11 * u11;
      P00 = n00; P01 = n01; P10 = n10; P11 = n11; V1 = nv1; V2 = nv2;
    }
  }
  if (lane == 63) {
    wm[wv][0] = P00; wm[wv][1] = P01; wm[wv][2] = P10; wm[wv][3] = P11;
    wm[wv][4] = V1;  wm[wv][5] = V2;
  }
  __syncthreads();
  double S1 = 0.0, S2 = 0.0;
  for (int w = 0; w < wv; ++w) {
    double n1 = wm[w][0] * S1 + wm[w][1] * S2 + wm[w][4];
    double n2 = wm[w][2] * S1 + wm[w][3] * S2 + wm[w][5];
    S1 = n1; S2 = n2;
  }
  double q00 = __shfl_up(P00, 1), q01 = __shfl_up(P01, 1);
  double q10 = __shfl_up(P10, 1), q11 = __shfl_up(P11, 1);
  double qv1 = __shfl_up(V1, 1),  qv2 = __shfl_up(V2, 1);
  double st1, st2;
  if (lane == 0) { st1 = S1; st2 = S2; }
  else { st1 = q00 * S1 + q01 * S2 + qv1; st2 = q10 * S1 + q11 * S2 + qv2; }
  float2* sp = s + (size_t)row * NCH;
  double s1v = st1, s2v = st2;
  for (int j = 0; j < OWNT; ++j) {
    int c = base + j;
    if (c < NCH) {
      sp[c] = make_float2((float)s1v, (float)s2v);
      double2 ev = ep[c];
      double n1 = m00 * s1v + m01 * s2v + ev.x;
      double n2 = m10 * s1v + m11 * s2v + ev.y;
      s1v = n1; s2v = n2;
    }
  }
}

// ---------------------------------------------------------------------------
// emit: thread owns ONE chunk for all phases.
// A: stage-1 f32 (exact seed), clipped vals -> registers v4[8].
// B: stage-2 zero-z local run, TRUE v-history (neighbor tail via shfl_up;
//    wave-boundary via tiny LDS). v4 -> zb; end state e2 = (z31, z30).
// C: s2 = e2[c-1] + M2*e2[c-2] (M2 = A2^32; M2^2 ~ 6e-6 truncated);
//    out[j] = clip(zb[j] + homogeneous(s2)[j]); writeback; coalesced store.
// Threads 252/253 handle warm slots 0/1 (A+B only); 254/255 idle in compute.
// ---------------------------------------------------------------------------
__global__ __launch_bounds__(256, 5) void emit_kernel(const float* __restrict__ x,
                                                      const float* __restrict__ nn,
                                                      const float2* __restrict__ s1,
                                                      const float* __restrict__ cx,
                                                      const float* __restrict__ cn,
                                                      float* __restrict__ out) {
  __shared__ float4 xs4[NF4];
  __shared__ float2 smt[4];   // tail boundary: reader wave w reads smt[w]
  __shared__ float2 sme[8];   // e2 boundary: lane0 up1=sme[2w+1], up2=sme[2w]; lane1 up2=sme[2w+1]
  const int tid = threadIdx.x;
  const int b = blockIdx.x;
  const int row = b / TILES, tile = b % TILES;
  const int c0 = tile * O_CH;
  const long g0 = (long)(c0 - 2) * CH;
  const float* src = (row < 64) ? x + (size_t)row * T_LEN
                                : nn + (size_t)(row - 64) * T_LEN;
  const float2* srow = s1 + (size_t)row * NCH;
  const float* cf = (row < 64) ? cx : cn;
  const float A1c = cf[0], A2c = cf[1], B1c = cf[2], B2c = cf[3];

  // ---- load tile (chunks c0-2 .. c0+251) ----
  for (int k = tid; k < NF4; k += 256) {
    long gi = g0 + 4L * k;
    float4 v = make_float4(0.f, 0.f, 0.f, 0.f);
    if (gi >= 0 && gi < T_LEN) v = *reinterpret_cast<const float4*>(src + gi);
    xs4[swz4(k)] = v;
  }
  __syncthreads();

  const int lane = tid & 63, wv = tid >> 6;
  int slot, chunk;
  if (tid < O_CH) { slot = tid + 2; chunk = c0 + tid; }
  else if (tid < O_CH + 2) { slot = tid - O_CH; chunk = c0 - 2 + slot; }
  else { slot = -1; chunk = NCH; }
  const bool act = (slot >= 0) && (chunk >= 0) && (chunk < NCH);

  float4 v4[8];
  float tail_x = 0.f, tail_y = 0.f;
  float ez1 = 0.f, ez2 = 0.f;

  // ---- phase A: stage-1, exact seed; v4 = clipped stage-1 ----
  if (act) {
    float y1 = 0.f, y2 = 0.f, x1 = 0.f, x2 = 0.f;
    if (chunk > 0) {
      float2 sv = srow[chunk];
      y1 = sv.x; y2 = sv.y;
      if (slot >= 1) {
        float4 pt = xs4[swz4((slot - 1) * 8 + 7)];
        x1 = pt.w; x2 = pt.z;
      } else {
        long gb = (long)chunk * CH;
        x1 = src[gb - 1]; x2 = src[gb - 2];
      }
    }
#pragma unroll
    for (int q = 0; q < 8; ++q) {
      float4 a = xs4[swz4(slot * 8 + q)];
      float4 o;
#define A1S(XT, OT) { float xt_ = (XT); \
      float yy = (xt_ - 2.f * x1 + x2) + (C1F * y1 + C2F * y2); \
      x2 = x1; x1 = xt_; y2 = y1; y1 = yy; OT = clip1f(yy); }
      A1S(a.x, o.x) A1S(a.y, o.y) A1S(a.z, o.z) A1S(a.w, o.w)
#undef A1S
      v4[q] = o;
    }
    tail_x = v4[7].w; tail_y = v4[7].z;          // v[31], v[30]
    if (lane == 63 && wv < 3) smt[wv + 1] = make_float2(tail_x, tail_y);
    if (tid == O_CH + 1)      smt[0]      = make_float2(tail_x, tail_y);
  }
  __syncthreads();

  // ---- phase B: stage-2 zero-z local run, true v-history; v4 -> zb ----
  if (act) {
    float v1, v2;
    if (slot == 0) {
      float2 sv = srow[chunk];                    // tail of chunk c0-3
      v1 = clip1f(sv.x); v2 = clip1f(sv.y);
    } else {
      float ux = __shfl_up(tail_x, 1);
      float uy = __shfl_up(tail_y, 1);
      if (lane == 0) { float2 tb = smt[wv]; ux = tb.x; uy = tb.y; }
      v1 = ux; v2 = uy;
    }
    if (chunk == 0) { v1 = 0.f; v2 = 0.f; }
    float z1 = 0.f, z2 = 0.f;
#pragma unroll
    for (int q = 0; q < 8; ++q) {
      float4 t = v4[q];
      float4 o;
#define BS(VV, OT) { float vv_ = (VV); \
      float zz = vv_ + B1c * v1 + B2c * v2 - A1c * z1 - A2c * z2; \
      v2 = v1; v1 = vv_; z2 = z1; z1 = zz; OT = zz; }
      BS(t.x, o.x) BS(t.y, o.y) BS(t.z, o.z) BS(t.w, o.w)
#undef BS
      v4[q] = o;
    }
    ez1 = z1; ez2 = z2;
    if (lane >= 62 && wv < 3) sme[2 * (wv + 1) + (lane & 1)] = make_float2(ez1, ez2);
    if (tid >= O_CH && tid < O_CH + 2) sme[tid - O_CH] = make_float2(ez1, ez2);
  }
  __syncthreads();

  // ---- phase C: homogeneous correction + clip + writeback ----
  if (tid < O_CH && act) {
    float pm2 = 0.f, pm1 = 0.f, p0 = 1.f;        // M2 = A2stage^CH via p-rec
#pragma unroll
    for (int k = 0; k < CH; ++k) {
      float pn = -A1c * p0 - A2c * pm1;
      pm2 = pm1; pm1 = p0; p0 = pn;
    }
    const float m00 = p0,  m01 = -A2c * pm1;
    const float m10 = pm1, m11 = -A2c * pm2;
    float u1x = __shfl_up(ez1, 1), u1y = __shfl_up(ez2, 1);
    float u2x = __shfl_up(ez1, 2), u2y = __shfl_up(ez2, 2);
    if (lane == 0) {
      float2 a = sme[2 * wv + 1]; u1x = a.x; u1y = a.y;
      float2 bq = sme[2 * wv];    u2x = bq.x; u2y = bq.y;
    } else if (lane == 1) {
      float2 bq = sme[2 * wv + 1]; u2x = bq.x; u2y = bq.y;
    }
    float s2x, s2y;
    if (chunk == 0)      { s2x = 0.f; s2y = 0.f; }
    else if (chunk == 1) { s2x = u1x; s2y = u1y; }
    else {
      s2x = u1x + m00 * u2x + m01 * u2y;
      s2y = u1y + m10 * u2x + m11 * u2y;
    }
    float h1 = s2x, h2 = s2y;
#pragma unroll
    for (int q = 0; q < 8; ++q) {
      float4 t = v4[q];
      float4 o;
#define CS(ZB, OT) { float hh = -A1c * h1 - A2c * h2; \
      OT = clip1f((ZB) + hh); h2 = h1; h1 = hh; }
      CS(t.x, o.x) CS(t.y, o.y) CS(t.z, o.z) CS(t.w, o.w)
#undef CS
      xs4[swz4(slot * 8 + q)] = o;
    }
  }
  __syncthreads();

  // ---- coalesced store of own chunks (slots 2..253) ----
  float* orow = out + (size_t)row * T_LEN;
  const long tile_start = (long)c0 * CH;
  for (int k = tid; k < O_CH * 8; k += 256) {
    long gi = tile_start + 4L * k;
    if (gi < T_LEN)
      *reinterpret_cast<float4*>(orow + gi) = xs4[swz4(16 + k)];
  }
}

// ---------------------------------------------------------------------------
extern "C" void kernel_launch(void* const* d_in, const int* in_sizes, int n_in,
                              void* d_out, int out_size, void* d_ws, size_t ws_size,
                              hipStream_t stream) {
  const float* x  = (const float*)d_in[0];   // (64, 160000)
  const float* nn = (const float*)d_in[1];   // (64, 160000)
  const float* cx = (const float*)d_in[2];   // (4,) a1,a2,b1,b2
  const float* cn = (const float*)d_in[3];   // (4,)
  float* out = (float*)d_out;                // (128, 160000) flat

  // e1 (f64, 10.24 MB) aliases d_out: written by pass_a1, consumed by
  // scan_row, then fully overwritten by emit. s1 (f32, 5.12 MB) in ws.
  double2* e1 = (double2*)d_out;
  float2*  s1 = (float2*)d_ws;

  const int total = NROW * NCH;              // 640000
  const int blk = 256;
  const int nb = (total + blk - 1) / blk;    // 2500

  pass_a1<<<nb, blk, 0, stream>>>(x, nn, e1);
  scan_row<<<NROW, blk, 0, stream>>>(e1, s1);
  emit_kernel<<<NBLK, blk, 0, stream>>>(x, nn, s1, cx, cn, out);
}